// Round 6
// baseline (323.159 us; speedup 1.0000x reference)
//
#include <hip/hip_runtime.h>
#include <stdint.h>

#define N_PTS 65536
#define NBINS 32768      // positive f32 -> bits>>16 in [0, 32768)
#define LCAP 1024        // LDS candidate capacity
typedef unsigned long long u64;

// ws layout
//   [0    , 256K)      scores  f32[65536]
//   [256K , 384K)      hist    u32[32768]
//   [384K , 384K+64)   done    u32 completion counter (zeroed by memset)

// ---------------------------------------------------------------------------
// Fused kernel. 256 blocks x 256 threads (1 block/CU).
//
// Scoring: 16-lane groups, REGISTER-RESIDENT weights (loaded once/thread):
//   lane g of each group holds  W1 rows {2g,2g+1} (12 regs),
//   W2 rows {4g..4g+3} (128 regs), Wa row q=g (64 regs), Wb row g&7 (16 regs).
// Activations (h1/v/h3) are shared through per-wave LDS slots. All sharing is
// intra-wave => wave-coherent LDS, NO barriers in the point loop. Two points
// (parity 0/1) are processed per iteration with separate LDS slots so their
// load/compute chains interleave.
//
// Select: last-block-done pattern (device-scope fence + atomic): the last
// block re-scans hist -> threshold T, compacts bin>=T scores into LDS,
// rank-selects top-64 (exact lax.top_k tie order via key (bits<<32)|~idx),
// and gathers out[b,k,c] = src[b,c,idx[k]].
// ---------------------------------------------------------------------------
__global__ __launch_bounds__(256, 1) void fused_kernel(
    const float* __restrict__ src,
    const float* __restrict__ W1, const float* __restrict__ b1,
    const float* __restrict__ W2, const float* __restrict__ b2,
    const float* __restrict__ Wa, const float* __restrict__ ba,
    const float* __restrict__ Wb, const float* __restrict__ bb,
    const float* __restrict__ Wc, const float* __restrict__ bc,
    float* __restrict__ scores, unsigned* __restrict__ hist,
    unsigned* __restrict__ done, float* __restrict__ out)
{
    // scoring buffers (per-wave slots, parity double-buffered)
    __shared__ __align__(16) float xb[256][8];
    __shared__ __align__(16) float h1b[4][2][4][32];
    __shared__ __align__(16) float vb [4][2][4][64];
    __shared__ __align__(16) float h3b[4][2][4][16];
    // epilogue buffers
    __shared__ unsigned csum[256];
    __shared__ unsigned bsum[128];
    __shared__ u64 keys[LCAP];
    __shared__ int idxs[64];
    __shared__ int sh_cnt, sh_T, sh_c;
    __shared__ unsigned sh_tail, sh_rank;

    const int t  = threadIdx.x;
    const int wv = t >> 6;        // wave in block
    const int ln = t & 63;        // lane in wave
    const int w  = ln >> 4;       // group in wave
    const int g  = ln & 15;       // lane in group

    // ---- stage this block's 256 points (thread t stages point t) ----
    {
        const int p = blockIdx.x * 256 + t;
        #pragma unroll
        for (int c = 0; c < 6; c++) xb[t][c] = src[c * N_PTS + p];
    }

    // ---- persistent weights into registers ----
    float w1A[6], w1B[6];
    #pragma unroll
    for (int c = 0; c < 6; c++) {
        w1A[c] = W1[(2 * g) * 6 + c];
        w1B[c] = W1[(2 * g + 1) * 6 + c];
    }
    const float b1A = b1[2 * g], b1B = b1[2 * g + 1];

    float w2[4][32], b2r[4];
    #pragma unroll
    for (int k = 0; k < 4; k++) {
        const float4* row = (const float4*)&W2[(4 * g + k) * 32];
        #pragma unroll
        for (int i = 0; i < 8; i++) {
            const float4 f = row[i];
            w2[k][4*i+0] = f.x; w2[k][4*i+1] = f.y;
            w2[k][4*i+2] = f.z; w2[k][4*i+3] = f.w;
        }
        b2r[k] = b2[4 * g + k];
    }

    float wa[64];
    {
        const float4* row = (const float4*)&Wa[g * 64];
        #pragma unroll
        for (int i = 0; i < 16; i++) {
            const float4 f = row[i];
            wa[4*i+0] = f.x; wa[4*i+1] = f.y;
            wa[4*i+2] = f.z; wa[4*i+3] = f.w;
        }
    }
    const float baG = ba[g];

    float wbr[16];
    const int j5 = g & 7;
    {
        const float4* row = (const float4*)&Wb[j5 * 16];
        #pragma unroll
        for (int i = 0; i < 4; i++) {
            const float4 f = row[i];
            wbr[4*i+0] = f.x; wbr[4*i+1] = f.y;
            wbr[4*i+2] = f.z; wbr[4*i+3] = f.w;
        }
    }
    const float bbJ = bb[j5], wcJ = Wc[j5], bcV = bc[0];

    const int lxbase = wv * 64 + w * 16;           // xb row base for group
    const int pbase  = blockIdx.x * 256 + lxbase;  // global point base

    // ---- point loop: 16 points per group, 2 per iteration ----
    #pragma unroll 1
    for (int it = 0; it < 8; it++) {
        const int iA = 2 * it, iB = iA + 1;

        // S1: layer 1 — lane computes h1 neurons 2g, 2g+1 for both points
        const float4 xA0 = *(const float4*)&xb[lxbase + iA][0];
        const float4 xA1 = *(const float4*)&xb[lxbase + iA][4];
        const float4 xB0 = *(const float4*)&xb[lxbase + iB][0];
        const float4 xB1 = *(const float4*)&xb[lxbase + iB][4];
        float hA0 = b1A, hA1 = b1B, hB0 = b1A, hB1 = b1B;
        hA0 = fmaf(w1A[0], xA0.x, hA0); hA0 = fmaf(w1A[1], xA0.y, hA0);
        hA0 = fmaf(w1A[2], xA0.z, hA0); hA0 = fmaf(w1A[3], xA0.w, hA0);
        hA0 = fmaf(w1A[4], xA1.x, hA0); hA0 = fmaf(w1A[5], xA1.y, hA0);
        hA1 = fmaf(w1B[0], xA0.x, hA1); hA1 = fmaf(w1B[1], xA0.y, hA1);
        hA1 = fmaf(w1B[2], xA0.z, hA1); hA1 = fmaf(w1B[3], xA0.w, hA1);
        hA1 = fmaf(w1B[4], xA1.x, hA1); hA1 = fmaf(w1B[5], xA1.y, hA1);
        hB0 = fmaf(w1A[0], xB0.x, hB0); hB0 = fmaf(w1A[1], xB0.y, hB0);
        hB0 = fmaf(w1A[2], xB0.z, hB0); hB0 = fmaf(w1A[3], xB0.w, hB0);
        hB0 = fmaf(w1A[4], xB1.x, hB0); hB0 = fmaf(w1A[5], xB1.y, hB0);
        hB1 = fmaf(w1B[0], xB0.x, hB1); hB1 = fmaf(w1B[1], xB0.y, hB1);
        hB1 = fmaf(w1B[2], xB0.z, hB1); hB1 = fmaf(w1B[3], xB0.w, hB1);
        hB1 = fmaf(w1B[4], xB1.x, hB1); hB1 = fmaf(w1B[5], xB1.y, hB1);
        {
            float2 fA; fA.x = fmaxf(hA0, 0.f); fA.y = fmaxf(hA1, 0.f);
            float2 fB; fB.x = fmaxf(hB0, 0.f); fB.y = fmaxf(hB1, 0.f);
            *(float2*)&h1b[wv][0][w][2 * g] = fA;
            *(float2*)&h1b[wv][1][w][2 * g] = fB;
        }

        // S2: layer 2 — 4 neurons/lane, weights in regs, h1 broadcast
        float vA0 = b2r[0], vA1 = b2r[1], vA2 = b2r[2], vA3 = b2r[3];
        float vB0 = b2r[0], vB1 = b2r[1], vB2 = b2r[2], vB3 = b2r[3];
        #pragma unroll
        for (int i4 = 0; i4 < 8; i4++) {
            const float4 hA = *(const float4*)&h1b[wv][0][w][4 * i4];
            const float4 hB = *(const float4*)&h1b[wv][1][w][4 * i4];
            vA0 = fmaf(w2[0][4*i4+0], hA.x, vA0); vA0 = fmaf(w2[0][4*i4+1], hA.y, vA0);
            vA0 = fmaf(w2[0][4*i4+2], hA.z, vA0); vA0 = fmaf(w2[0][4*i4+3], hA.w, vA0);
            vA1 = fmaf(w2[1][4*i4+0], hA.x, vA1); vA1 = fmaf(w2[1][4*i4+1], hA.y, vA1);
            vA1 = fmaf(w2[1][4*i4+2], hA.z, vA1); vA1 = fmaf(w2[1][4*i4+3], hA.w, vA1);
            vA2 = fmaf(w2[2][4*i4+0], hA.x, vA2); vA2 = fmaf(w2[2][4*i4+1], hA.y, vA2);
            vA2 = fmaf(w2[2][4*i4+2], hA.z, vA2); vA2 = fmaf(w2[2][4*i4+3], hA.w, vA2);
            vA3 = fmaf(w2[3][4*i4+0], hA.x, vA3); vA3 = fmaf(w2[3][4*i4+1], hA.y, vA3);
            vA3 = fmaf(w2[3][4*i4+2], hA.z, vA3); vA3 = fmaf(w2[3][4*i4+3], hA.w, vA3);
            vB0 = fmaf(w2[0][4*i4+0], hB.x, vB0); vB0 = fmaf(w2[0][4*i4+1], hB.y, vB0);
            vB0 = fmaf(w2[0][4*i4+2], hB.z, vB0); vB0 = fmaf(w2[0][4*i4+3], hB.w, vB0);
            vB1 = fmaf(w2[1][4*i4+0], hB.x, vB1); vB1 = fmaf(w2[1][4*i4+1], hB.y, vB1);
            vB1 = fmaf(w2[1][4*i4+2], hB.z, vB1); vB1 = fmaf(w2[1][4*i4+3], hB.w, vB1);
            vB2 = fmaf(w2[2][4*i4+0], hB.x, vB2); vB2 = fmaf(w2[2][4*i4+1], hB.y, vB2);
            vB2 = fmaf(w2[2][4*i4+2], hB.z, vB2); vB2 = fmaf(w2[2][4*i4+3], hB.w, vB2);
            vB3 = fmaf(w2[3][4*i4+0], hB.x, vB3); vB3 = fmaf(w2[3][4*i4+1], hB.y, vB3);
            vB3 = fmaf(w2[3][4*i4+2], hB.z, vB3); vB3 = fmaf(w2[3][4*i4+3], hB.w, vB3);
        }
        {
            float4 fA; fA.x = fmaxf(vA0,0.f); fA.y = fmaxf(vA1,0.f);
                       fA.z = fmaxf(vA2,0.f); fA.w = fmaxf(vA3,0.f);
            float4 fB; fB.x = fmaxf(vB0,0.f); fB.y = fmaxf(vB1,0.f);
                       fB.z = fmaxf(vB2,0.f); fB.w = fmaxf(vB3,0.f);
            *(float4*)&vb[wv][0][w][4 * g] = fA;
            *(float4*)&vb[wv][1][w][4 * g] = fB;
        }

        // S3: layer 3 — lane computes h3[q=g], Wa row in regs, v broadcast
        float aA = baG, aB = baG;
        #pragma unroll
        for (int i4 = 0; i4 < 16; i4++) {
            const float4 vA4 = *(const float4*)&vb[wv][0][w][4 * i4];
            const float4 vB4 = *(const float4*)&vb[wv][1][w][4 * i4];
            aA = fmaf(wa[4*i4+0], vA4.x, aA); aA = fmaf(wa[4*i4+1], vA4.y, aA);
            aA = fmaf(wa[4*i4+2], vA4.z, aA); aA = fmaf(wa[4*i4+3], vA4.w, aA);
            aB = fmaf(wa[4*i4+0], vB4.x, aB); aB = fmaf(wa[4*i4+1], vB4.y, aB);
            aB = fmaf(wa[4*i4+2], vB4.z, aB); aB = fmaf(wa[4*i4+3], vB4.w, aB);
        }
        h3b[wv][0][w][g] = fmaxf(aA, 0.f);
        h3b[wv][1][w][g] = fmaxf(aB, 0.f);

        // S4: layers 4+5 — lane computes u-neuron j5=g&7, butterfly over 8
        float uA = bbJ, uB = bbJ;
        #pragma unroll
        for (int q4 = 0; q4 < 4; q4++) {
            const float4 hA = *(const float4*)&h3b[wv][0][w][4 * q4];
            const float4 hB = *(const float4*)&h3b[wv][1][w][4 * q4];
            uA = fmaf(wbr[4*q4+0], hA.x, uA); uA = fmaf(wbr[4*q4+1], hA.y, uA);
            uA = fmaf(wbr[4*q4+2], hA.z, uA); uA = fmaf(wbr[4*q4+3], hA.w, uA);
            uB = fmaf(wbr[4*q4+0], hB.x, uB); uB = fmaf(wbr[4*q4+1], hB.y, uB);
            uB = fmaf(wbr[4*q4+2], hB.z, uB); uB = fmaf(wbr[4*q4+3], hB.w, uB);
        }
        float zpA = wcJ * fmaxf(uA, 0.f);
        float zpB = wcJ * fmaxf(uB, 0.f);
        zpA += __shfl_xor(zpA, 1); zpA += __shfl_xor(zpA, 2); zpA += __shfl_xor(zpA, 4);
        zpB += __shfl_xor(zpB, 1); zpB += __shfl_xor(zpB, 2); zpB += __shfl_xor(zpB, 4);
        if (g == 0) {
            const float zA = zpA + bcV;
            const float zB = zpB + bcV;
            const float spA = fmaxf(zA, 0.f) + log1pf(expf(-fabsf(zA)));
            const float spB = fmaxf(zB, 0.f) + log1pf(expf(-fabsf(zB)));
            scores[pbase + iA] = spA;
            scores[pbase + iB] = spB;
            atomicAdd(&hist[__float_as_uint(spA) >> 16], 1u);
            atomicAdd(&hist[__float_as_uint(spB) >> 16], 1u);
        }
    }

    // ---- completion: last block runs the select + gather epilogue ----
    __syncthreads();
    __threadfence();                       // release scores/hist device-wide
    if (t == 0) sh_rank = atomicAdd(done, 1u);
    __syncthreads();
    if (sh_rank != (unsigned)(gridDim.x - 1)) return;
    __threadfence();                       // acquire other blocks' writes

    // (a) threshold: T = max bin with suffix-count >= 64
    {
        unsigned s = 0;
        const uint4* h4 = (const uint4*)(hist + t * 128);
        #pragma unroll
        for (int i = 0; i < 32; i++) {
            const uint4 v = h4[i];
            s += v.x + v.y + v.z + v.w;
        }
        csum[t] = s;
    }
    __syncthreads();
    for (int d = 1; d < 256; d <<= 1) {
        const unsigned v = (t + d < 256) ? csum[t + d] : 0u;
        __syncthreads();
        csum[t] += v;
        __syncthreads();
    }
    {
        const unsigned here = csum[t];
        const unsigned nxt = (t + 1 < 256) ? csum[t + 1] : 0u;
        if (here >= 64u && nxt < 64u) { sh_c = t; sh_tail = nxt; }
    }
    __syncthreads();
    const int cstar = sh_c;
    const unsigned tail = sh_tail;
    if (t < 128) bsum[t] = hist[cstar * 128 + t];
    __syncthreads();
    for (int d = 1; d < 128; d <<= 1) {
        unsigned v = 0u;
        if (t < 128 && t + d < 128) v = bsum[t + d];
        __syncthreads();
        if (t < 128) bsum[t] += v;
        __syncthreads();
    }
    if (t < 128) {
        const unsigned here = bsum[t] + tail;
        const unsigned nxt = (t + 1 < 128) ? bsum[t + 1] + tail : tail;
        if (here >= 64u && nxt < 64u) sh_T = cstar * 128 + t;
    }
    if (t == 0) sh_cnt = 0;
    __syncthreads();
    const int T = sh_T;

    // (b) compact candidates (bin >= T) into LDS
    {
        const float4* s4 = (const float4*)scores;
        for (int i = t; i < N_PTS / 4; i += 256) {
            const float4 v = s4[i];
            const int n0 = 4 * i;
            unsigned b;
            b = __float_as_uint(v.x);
            if ((int)(b >> 16) >= T) { int p = atomicAdd(&sh_cnt, 1); if (p < LCAP) keys[p] = ((u64)b << 32) | (unsigned)~(n0 + 0); }
            b = __float_as_uint(v.y);
            if ((int)(b >> 16) >= T) { int p = atomicAdd(&sh_cnt, 1); if (p < LCAP) keys[p] = ((u64)b << 32) | (unsigned)~(n0 + 1); }
            b = __float_as_uint(v.z);
            if ((int)(b >> 16) >= T) { int p = atomicAdd(&sh_cnt, 1); if (p < LCAP) keys[p] = ((u64)b << 32) | (unsigned)~(n0 + 2); }
            b = __float_as_uint(v.w);
            if ((int)(b >> 16) >= T) { int p = atomicAdd(&sh_cnt, 1); if (p < LCAP) keys[p] = ((u64)b << 32) | (unsigned)~(n0 + 3); }
        }
    }
    __syncthreads();

    // (c) rank-select top-64 (exact lax.top_k tie order; keys unique)
    int count = sh_cnt;
    if (count > LCAP) count = LCAP;
    for (int i = t; i < count; i += 256) {
        const u64 me = keys[i];
        int r = 0;
        for (int j = 0; j < count; j++) r += (keys[j] > me);
        if (r < 64) idxs[r] = (int)~(unsigned)(me & 0xFFFFFFFFu);
    }
    __syncthreads();

    // (d) gather: out[b, k, c] = src[b, c, idx[k]]
    for (int e = t; e < 3072; e += 256) {
        const int b  = e / 384;
        const int rr = e % 384;
        const int kk = rr / 6;
        const int c  = rr % 6;
        out[e] = src[(b * 6 + c) * N_PTS + idxs[kk]];
    }
}

extern "C" void kernel_launch(void* const* d_in, const int* in_sizes, int n_in,
                              void* d_out, int out_size, void* d_ws, size_t ws_size,
                              hipStream_t stream)
{
    const float* src = (const float*)d_in[0];
    const float* W1 = (const float*)d_in[2];
    const float* b1 = (const float*)d_in[3];
    const float* W2 = (const float*)d_in[4];
    const float* b2 = (const float*)d_in[5];
    const float* Wa = (const float*)d_in[6];
    const float* ba = (const float*)d_in[7];
    const float* Wb = (const float*)d_in[8];
    const float* bb = (const float*)d_in[9];
    const float* Wc = (const float*)d_in[10];
    const float* bc = (const float*)d_in[11];

    char* ws = (char*)d_ws;
    float*    scores = (float*)ws;                          // 256 KB
    unsigned* hist   = (unsigned*)(ws + 256 * 1024);        // 128 KB
    unsigned* done   = (unsigned*)(ws + 384 * 1024);        // 4 B
    float*    out    = (float*)d_out;

    // zero hist + done counter
    hipMemsetAsync(hist, 0, NBINS * sizeof(unsigned) + 64, stream);
    fused_kernel<<<256, 256, 0, stream>>>(src, W1, b1, W2, b2, Wa, ba,
                                          Wb, bb, Wc, bc, scores, hist,
                                          done, out);
}

// Round 7
// 209.696 us; speedup vs baseline: 1.5411x; 1.5411x over previous
//
#include <hip/hip_runtime.h>
#include <stdint.h>

#define N_PTS 65536
#define NBINS 32768      // positive f32 -> bits>>16 in [0, 32768)
#define CAND_CAP 4096
typedef unsigned long long u64;

// ws layout
//   [0    , 256K)      scores  f32[65536]
//   [256K , 384K)      hist    u32[32768]
//   [384K , 384K+64)   meta    i32 {0: cand_count}
//   [384K+64, +32K)    cand    u64[4096]

__global__ __launch_bounds__(256) void zero_kernel(unsigned* __restrict__ hist,
                                                   int* __restrict__ meta)
{
    const int i = blockIdx.x * 256 + threadIdx.x;
    hist[i] = 0u;
    if (i < 4) meta[i] = 0;
}

// ---------------------------------------------------------------------------
// K1: MLP score (batch 0). 256 blocks x 128 threads (2 waves/CU), TWO whole
// points per thread (p0 = base+t, p1 = base+128+t). No cross-lane sharing,
// no barriers in the loop, all LDS reads wave-uniform b128 broadcasts
// (conflict-free). The 64-neuron layer-2/3 loop is explicitly ping-pong
// software-pipelined: W2/WaT row j+1 prefetched into named float4 registers
// while row j is consumed -> cross-iteration load independence the compiler
// provably didn't create on its own (R5: VGPR_Count 52).
// Each b128 load feeds 8-16 FMAs (2 points x 4 weights).
// ---------------------------------------------------------------------------
__global__ __launch_bounds__(128, 1) void score_kernel(
    const float* __restrict__ src,
    const float* __restrict__ W1, const float* __restrict__ b1,
    const float* __restrict__ W2, const float* __restrict__ b2,
    const float* __restrict__ Wa, const float* __restrict__ ba,
    const float* __restrict__ Wb, const float* __restrict__ bb,
    const float* __restrict__ Wc, const float* __restrict__ bc,
    float* __restrict__ scores, unsigned* __restrict__ hist)
{
    __shared__ __align__(16) float sW1[32 * 8];    // [j][0:6]=w, [6]=bias, [7]=0
    __shared__ __align__(16) float sW2[64 * 32];   // [j][i]
    __shared__ __align__(16) float sWaT[64 * 16];  // [j][q] (transposed Wa)
    __shared__ __align__(16) float sWb[8 * 16];    // [j][q]
    __shared__ float sb2[64], sba[16], sbb[8], sWc[8], sbc1[1];
    const int t = threadIdx.x;

    // global x loads first (independent of LDS staging)
    const int base = blockIdx.x * 256;
    const int p0 = base + t, p1 = base + 128 + t;
    float xa[6], xc[6];
    #pragma unroll
    for (int c = 0; c < 6; c++) {
        xa[c] = src[c * N_PTS + p0];
        xc[c] = src[c * N_PTS + p1];
    }

    // stage weights
    for (int i = t; i < 256; i += 128) {
        const int j = i >> 3, c = i & 7;
        sW1[i] = (c < 6) ? W1[j * 6 + c] : ((c == 6) ? b1[j] : 0.f);
    }
    for (int i = t; i < 2048; i += 128) sW2[i] = W2[i];
    for (int i = t; i < 1024; i += 128) {
        const int j = i >> 4, q = i & 15;
        sWaT[i] = Wa[q * 64 + j];
    }
    if (t < 64)  sb2[t] = b2[t];
    if (t < 128) sWb[t] = Wb[t];
    if (t < 16)  sba[t] = ba[t];
    if (t < 8)   { sbb[t] = bb[t]; sWc[t] = Wc[t]; }
    if (t == 0)  sbc1[0] = bc[0];
    __syncthreads();

    // ---- layer 1: 6 -> 32, both points ----
    float h1a[32], h1c[32];
    #pragma unroll
    for (int j = 0; j < 32; j++) {
        const float4 wA = *(const float4*)&sW1[j * 8];
        const float4 wB = *(const float4*)&sW1[j * 8 + 4];   // .z = bias
        float sa = wB.z, sc = wB.z;
        sa = fmaf(wA.x, xa[0], sa); sa = fmaf(wA.y, xa[1], sa);
        sa = fmaf(wA.z, xa[2], sa); sa = fmaf(wA.w, xa[3], sa);
        sa = fmaf(wB.x, xa[4], sa); sa = fmaf(wB.y, xa[5], sa);
        sc = fmaf(wA.x, xc[0], sc); sc = fmaf(wA.y, xc[1], sc);
        sc = fmaf(wA.z, xc[2], sc); sc = fmaf(wA.w, xc[3], sc);
        sc = fmaf(wB.x, xc[4], sc); sc = fmaf(wB.y, xc[5], sc);
        h1a[j] = fmaxf(sa, 0.f);
        h1c[j] = fmaxf(sc, 0.f);
    }

    // ---- layers 2+3 fused: 32 -> 64 -> 16, ping-pong pipelined ----
    float h3a[16], h3c[16];
    #pragma unroll
    for (int q = 0; q < 16; q++) { h3a[q] = sba[q]; h3c[q] = sba[q]; }

    const float4* w2r = (const float4*)sW2;    // row j = w2r[j*8 + i]
    const float4* war = (const float4*)sWaT;   // row j = war[j*4 + i]

    float4 cur[8], wacur[4];
    #pragma unroll
    for (int i = 0; i < 8; i++) cur[i] = w2r[i];
    #pragma unroll
    for (int i = 0; i < 4; i++) wacur[i] = war[i];

#define L23_BODY(JIDX, BUF, WABUF)                                          \
    {                                                                       \
        float a0 = 0.f, a1 = 0.f, c0 = 0.f, c1 = 0.f;                       \
        _Pragma("unroll")                                                   \
        for (int i = 0; i < 8; i++) {                                       \
            const float4 w = BUF[i];                                        \
            a0 = fmaf(w.x, h1a[4*i+0], a0); a1 = fmaf(w.y, h1a[4*i+1], a1); \
            a0 = fmaf(w.z, h1a[4*i+2], a0); a1 = fmaf(w.w, h1a[4*i+3], a1); \
            c0 = fmaf(w.x, h1c[4*i+0], c0); c1 = fmaf(w.y, h1c[4*i+1], c1); \
            c0 = fmaf(w.z, h1c[4*i+2], c0); c1 = fmaf(w.w, h1c[4*i+3], c1); \
        }                                                                   \
        const float bj = sb2[JIDX];                                         \
        const float va = fmaxf(a0 + a1 + bj, 0.f);                          \
        const float vc = fmaxf(c0 + c1 + bj, 0.f);                          \
        _Pragma("unroll")                                                   \
        for (int q4 = 0; q4 < 4; q4++) {                                    \
            const float4 w = WABUF[q4];                                     \
            h3a[4*q4+0] = fmaf(w.x, va, h3a[4*q4+0]);                       \
            h3a[4*q4+1] = fmaf(w.y, va, h3a[4*q4+1]);                       \
            h3a[4*q4+2] = fmaf(w.z, va, h3a[4*q4+2]);                       \
            h3a[4*q4+3] = fmaf(w.w, va, h3a[4*q4+3]);                       \
            h3c[4*q4+0] = fmaf(w.x, vc, h3c[4*q4+0]);                       \
            h3c[4*q4+1] = fmaf(w.y, vc, h3c[4*q4+1]);                       \
            h3c[4*q4+2] = fmaf(w.z, vc, h3c[4*q4+2]);                       \
            h3c[4*q4+3] = fmaf(w.w, vc, h3c[4*q4+3]);                       \
        }                                                                   \
    }

    #pragma unroll 1
    for (int jj = 0; jj < 32; jj++) {
        const int j0 = 2 * jj, j1 = j0 + 1, j2 = (j0 + 2) & 63;
        // prefetch row j1 into nxt
        float4 nxt[8], wanxt[4];
        #pragma unroll
        for (int i = 0; i < 8; i++) nxt[i] = w2r[j1 * 8 + i];
        #pragma unroll
        for (int i = 0; i < 4; i++) wanxt[i] = war[j1 * 4 + i];
        // compute j0 from cur
        L23_BODY(j0, cur, wacur)
        // prefetch row j2 into cur (wraps harmlessly on last iter)
        #pragma unroll
        for (int i = 0; i < 8; i++) cur[i] = w2r[j2 * 8 + i];
        #pragma unroll
        for (int i = 0; i < 4; i++) wacur[i] = war[j2 * 4 + i];
        // compute j1 from nxt
        L23_BODY(j1, nxt, wanxt)
    }
#undef L23_BODY

    #pragma unroll
    for (int q = 0; q < 16; q++) {
        h3a[q] = fmaxf(h3a[q], 0.f);
        h3c[q] = fmaxf(h3c[q], 0.f);
    }

    // ---- layers 4+5: 16 -> 8 -> 1, both points ----
    const float4* wbr = (const float4*)sWb;
    float za = sbc1[0], zc = sbc1[0];
    #pragma unroll
    for (int j5 = 0; j5 < 8; j5++) {
        const float4 w0 = wbr[j5 * 4 + 0], w1 = wbr[j5 * 4 + 1];
        const float4 w2 = wbr[j5 * 4 + 2], w3 = wbr[j5 * 4 + 3];
        const float bj = sbb[j5];
        float sa0 = bj, sa1 = 0.f, sc0 = bj, sc1 = 0.f;
        sa0 = fmaf(w0.x, h3a[0],  sa0); sa1 = fmaf(w0.y, h3a[1],  sa1);
        sa0 = fmaf(w0.z, h3a[2],  sa0); sa1 = fmaf(w0.w, h3a[3],  sa1);
        sa0 = fmaf(w1.x, h3a[4],  sa0); sa1 = fmaf(w1.y, h3a[5],  sa1);
        sa0 = fmaf(w1.z, h3a[6],  sa0); sa1 = fmaf(w1.w, h3a[7],  sa1);
        sa0 = fmaf(w2.x, h3a[8],  sa0); sa1 = fmaf(w2.y, h3a[9],  sa1);
        sa0 = fmaf(w2.z, h3a[10], sa0); sa1 = fmaf(w2.w, h3a[11], sa1);
        sa0 = fmaf(w3.x, h3a[12], sa0); sa1 = fmaf(w3.y, h3a[13], sa1);
        sa0 = fmaf(w3.z, h3a[14], sa0); sa1 = fmaf(w3.w, h3a[15], sa1);
        sc0 = fmaf(w0.x, h3c[0],  sc0); sc1 = fmaf(w0.y, h3c[1],  sc1);
        sc0 = fmaf(w0.z, h3c[2],  sc0); sc1 = fmaf(w0.w, h3c[3],  sc1);
        sc0 = fmaf(w1.x, h3c[4],  sc0); sc1 = fmaf(w1.y, h3c[5],  sc1);
        sc0 = fmaf(w1.z, h3c[6],  sc0); sc1 = fmaf(w1.w, h3c[7],  sc1);
        sc0 = fmaf(w2.x, h3c[8],  sc0); sc1 = fmaf(w2.y, h3c[9],  sc1);
        sc0 = fmaf(w2.z, h3c[10], sc0); sc1 = fmaf(w2.w, h3c[11], sc1);
        sc0 = fmaf(w3.x, h3c[12], sc0); sc1 = fmaf(w3.y, h3c[13], sc1);
        sc0 = fmaf(w3.z, h3c[14], sc0); sc1 = fmaf(w3.w, h3c[15], sc1);
        const float wc = sWc[j5];
        za = fmaf(wc, fmaxf(sa0 + sa1, 0.f), za);
        zc = fmaf(wc, fmaxf(sc0 + sc1, 0.f), zc);
    }

    const float spa = fmaxf(za, 0.f) + log1pf(expf(-fabsf(za)));
    const float spc = fmaxf(zc, 0.f) + log1pf(expf(-fabsf(zc)));
    scores[p0] = spa;
    scores[p1] = spc;
    atomicAdd(&hist[__float_as_uint(spa) >> 16], 1u);
    atomicAdd(&hist[__float_as_uint(spc) >> 16], 1u);
}

// ---------------------------------------------------------------------------
// K2: threshold scan + compact. 64 blocks x 256 threads (unchanged from R5 —
// each block redundantly finds T = max bin with suffix >= 64, then compacts
// its 1024-score slice). Key = (score_bits<<32) | ~idx -> exact lax.top_k
// tie order (value desc, lower idx first).
// ---------------------------------------------------------------------------
__global__ __launch_bounds__(256) void compact_kernel(
    const unsigned* __restrict__ hist, const float* __restrict__ scores,
    int* __restrict__ meta, u64* __restrict__ cand)
{
    __shared__ unsigned csum[256];
    __shared__ unsigned bsum[128];
    __shared__ int sh_c, sh_T;
    __shared__ unsigned sh_tail;
    const int t = threadIdx.x;

    {
        unsigned s = 0;
        const uint4* h4 = (const uint4*)(hist + t * 128);
        #pragma unroll
        for (int i = 0; i < 32; i++) {
            const uint4 v = h4[i];
            s += v.x + v.y + v.z + v.w;
        }
        csum[t] = s;
    }
    __syncthreads();
    for (int d = 1; d < 256; d <<= 1) {
        const unsigned v = (t + d < 256) ? csum[t + d] : 0u;
        __syncthreads();
        csum[t] += v;
        __syncthreads();
    }
    {
        const unsigned here = csum[t];
        const unsigned nxt = (t + 1 < 256) ? csum[t + 1] : 0u;
        if (here >= 64u && nxt < 64u) { sh_c = t; sh_tail = nxt; }
    }
    __syncthreads();
    const int cstar = sh_c;
    const unsigned tail = sh_tail;

    if (t < 128) bsum[t] = hist[cstar * 128 + t];
    __syncthreads();
    for (int d = 1; d < 128; d <<= 1) {
        unsigned v = 0u;
        if (t < 128 && t + d < 128) v = bsum[t + d];
        __syncthreads();
        if (t < 128) bsum[t] += v;
        __syncthreads();
    }
    if (t < 128) {
        const unsigned here = bsum[t] + tail;
        const unsigned nxt = (t + 1 < 128) ? bsum[t + 1] + tail : tail;
        if (here >= 64u && nxt < 64u) sh_T = cstar * 128 + t;
    }
    __syncthreads();
    const int T = sh_T;

    const float4* s4 = (const float4*)scores;
    const int i = blockIdx.x * 256 + t;
    const float4 v = s4[i];
    const int n0 = 4 * i;
    unsigned b;
    b = __float_as_uint(v.x);
    if ((int)(b >> 16) >= T) { int p = atomicAdd(&meta[0], 1); if (p < CAND_CAP) cand[p] = ((u64)b << 32) | (unsigned)~(n0 + 0); }
    b = __float_as_uint(v.y);
    if ((int)(b >> 16) >= T) { int p = atomicAdd(&meta[0], 1); if (p < CAND_CAP) cand[p] = ((u64)b << 32) | (unsigned)~(n0 + 1); }
    b = __float_as_uint(v.z);
    if ((int)(b >> 16) >= T) { int p = atomicAdd(&meta[0], 1); if (p < CAND_CAP) cand[p] = ((u64)b << 32) | (unsigned)~(n0 + 2); }
    b = __float_as_uint(v.w);
    if ((int)(b >> 16) >= T) { int p = atomicAdd(&meta[0], 1); if (p < CAND_CAP) cand[p] = ((u64)b << 32) | (unsigned)~(n0 + 3); }
}

// ---------------------------------------------------------------------------
// K3: rank-select (O(count^2), count ~ 100) + gather. 1 block x 256.
// ---------------------------------------------------------------------------
__global__ __launch_bounds__(256) void final_kernel(
    const int* __restrict__ meta, const u64* __restrict__ cand,
    const float* __restrict__ src, float* __restrict__ out)
{
    __shared__ u64 keys[CAND_CAP];
    __shared__ int idxs[64];
    const int t = threadIdx.x;

    int count = meta[0];
    if (count > CAND_CAP) count = CAND_CAP;

    for (int i = t; i < count; i += 256) keys[i] = cand[i];
    __syncthreads();

    for (int i = t; i < count; i += 256) {
        const u64 me = keys[i];
        int r = 0;
        for (int j = 0; j < count; j++) r += (keys[j] > me);
        if (r < 64) idxs[r] = (int)~(unsigned)(me & 0xFFFFFFFFu);
    }
    __syncthreads();

    // out[b, k, c] = src[b, c, idx[k]]  -> flat e = b*384 + k*6 + c
    for (int e = t; e < 3072; e += 256) {
        const int b  = e / 384;
        const int rr = e % 384;
        const int kk = rr / 6;
        const int c  = rr % 6;
        out[e] = src[(b * 6 + c) * N_PTS + idxs[kk]];
    }
}

extern "C" void kernel_launch(void* const* d_in, const int* in_sizes, int n_in,
                              void* d_out, int out_size, void* d_ws, size_t ws_size,
                              hipStream_t stream)
{
    const float* src = (const float*)d_in[0];
    const float* W1 = (const float*)d_in[2];
    const float* b1 = (const float*)d_in[3];
    const float* W2 = (const float*)d_in[4];
    const float* b2 = (const float*)d_in[5];
    const float* Wa = (const float*)d_in[6];
    const float* ba = (const float*)d_in[7];
    const float* Wb = (const float*)d_in[8];
    const float* bb = (const float*)d_in[9];
    const float* Wc = (const float*)d_in[10];
    const float* bc = (const float*)d_in[11];

    char* ws = (char*)d_ws;
    float*    scores = (float*)ws;                          // 256 KB
    unsigned* hist   = (unsigned*)(ws + 256 * 1024);        // 128 KB
    int*      meta   = (int*)(ws + 384 * 1024);             // 64 B
    u64*      cand   = (u64*)(ws + 384 * 1024 + 64);        // 32 KB
    float*    out    = (float*)d_out;

    zero_kernel<<<NBINS / 256, 256, 0, stream>>>(hist, meta);   // no memsetAsync (~80us in graph replay!)
    score_kernel<<<256, 128, 0, stream>>>(src, W1, b1, W2, b2, Wa, ba,
                                          Wb, bb, Wc, bc, scores, hist);
    compact_kernel<<<64, 256, 0, stream>>>(hist, scores, meta, cand);
    final_kernel<<<1, 256, 0, stream>>>(meta, cand, src, out);
}

// Round 8
// 145.503 us; speedup vs baseline: 2.2210x; 1.4412x over previous
//
#include <hip/hip_runtime.h>
#include <stdint.h>

#define N_PTS 65536
#define NB1 32768        // level-1 bins: score bits 31:16
#define NB2 65536        // level-2 bins: score bits 15:0 (within bin B*)
#define CAND_CAP 4096
typedef unsigned long long u64;

// ws layout (contiguous zero region [256K, 256K+384K+64))
//   [0    , 256K)        scores  f32[65536]
//   [256K , 384K)        hist1   u32[32768]
//   [384K , 640K)        hist2   u32[65536]
//   [640K , 640K+64)     meta    i32 {0:Bstar, 1:tail1, 2:cand_count}
//   [640K+64, +32K)      cand    u64[4096]

__global__ __launch_bounds__(256) void zero_kernel(unsigned* __restrict__ z, int n)
{
    const int i = blockIdx.x * 256 + threadIdx.x;
    if (i < n) z[i] = 0u;
}

// ---------------------------------------------------------------------------
// K1: MLP score (batch 0), R5 structure (fastest variant: 1 pt/thread,
// wave-uniform b128 broadcast weights) + LDS-PRIVATE histogram.
// Theory: the 65536 global atomicAdds into a few hot bins serialized on L2
// (~100us in R1-R7). LDS atomics absorb intra-block contention; the merge
// issues <=256 nonzero-bin global atomics per block.
// LDS: 128K hist + 14.3K weights = 145K (1 block/CU, grid=256).
// ---------------------------------------------------------------------------
__global__ __launch_bounds__(256, 1) void score_kernel(
    const float* __restrict__ src,
    const float* __restrict__ W1, const float* __restrict__ b1,
    const float* __restrict__ W2, const float* __restrict__ b2,
    const float* __restrict__ Wa, const float* __restrict__ ba,
    const float* __restrict__ Wb, const float* __restrict__ bb,
    const float* __restrict__ Wc, const float* __restrict__ bc,
    float* __restrict__ scores, unsigned* __restrict__ hist1)
{
    __shared__ unsigned histL[NB1];                // 128 KB
    __shared__ __align__(16) float sW1[32 * 8];    // [j][0:6]=w, [6]=bias
    __shared__ __align__(16) float sW2[64 * 32];
    __shared__ __align__(16) float sWaT[64 * 16];  // [j][q] (transposed Wa)
    __shared__ __align__(16) float sWb[8 * 16];
    __shared__ float sb2[64], sba[16], sbb[8], sWc[8], sbc1[1];
    const int t = threadIdx.x;

    // zero LDS hist (uint4 stores)
    {
        uint4* h4 = (uint4*)histL;
        const uint4 zz = {0u, 0u, 0u, 0u};
        #pragma unroll
        for (int i = 0; i < 32; i++) h4[t + 256 * i] = zz;
    }

    // stage weights
    {
        const int j = t >> 3, c = t & 7;
        sW1[t] = (c < 6) ? W1[j * 6 + c] : ((c == 6) ? b1[j] : 0.f);
    }
    for (int i = t; i < 2048; i += 256) sW2[i] = W2[i];
    for (int i = t; i < 1024; i += 256) {
        const int j = i >> 4, q = i & 15;
        sWaT[i] = Wa[q * 64 + j];
    }
    if (t < 128) sWb[t] = Wb[t];
    if (t < 64)  sb2[t] = b2[t];
    if (t < 16)  sba[t] = ba[t];
    if (t < 8)   { sbb[t] = bb[t]; sWc[t] = Wc[t]; }
    if (t == 0)  sbc1[0] = bc[0];
    __syncthreads();

    const int p = blockIdx.x * 256 + t;
    float x0 = src[0 * N_PTS + p], x1 = src[1 * N_PTS + p];
    float x2 = src[2 * N_PTS + p], x3 = src[3 * N_PTS + p];
    float x4 = src[4 * N_PTS + p], x5 = src[5 * N_PTS + p];

    // layer 1: 6 -> 32
    float h1[32];
    #pragma unroll
    for (int j = 0; j < 32; j++) {
        const float4 wA = *(const float4*)&sW1[j * 8];
        const float4 wB = *(const float4*)&sW1[j * 8 + 4];   // .z = bias
        float a = wB.z;
        a = fmaf(wA.x, x0, a); a = fmaf(wA.y, x1, a);
        a = fmaf(wA.z, x2, a); a = fmaf(wA.w, x3, a);
        a = fmaf(wB.x, x4, a); a = fmaf(wB.y, x5, a);
        h1[j] = fmaxf(a, 0.f);
    }

    // layers 2+3 fused: 32 -> 64 -> 16
    float h3[16];
    #pragma unroll
    for (int q = 0; q < 16; q++) h3[q] = sba[q];

    #pragma unroll 4
    for (int j = 0; j < 64; j++) {
        const float4* w2r = (const float4*)&sW2[j * 32];
        float a0 = 0.f, a1 = 0.f, a2 = 0.f, a3 = 0.f;
        #pragma unroll
        for (int i4 = 0; i4 < 8; i4++) {
            const float4 w = w2r[i4];
            a0 = fmaf(w.x, h1[4 * i4 + 0], a0);
            a1 = fmaf(w.y, h1[4 * i4 + 1], a1);
            a2 = fmaf(w.z, h1[4 * i4 + 2], a2);
            a3 = fmaf(w.w, h1[4 * i4 + 3], a3);
        }
        const float v = fmaxf((a0 + a1) + (a2 + a3) + sb2[j], 0.f);
        const float4* war = (const float4*)&sWaT[j * 16];
        #pragma unroll
        for (int q4 = 0; q4 < 4; q4++) {
            const float4 w = war[q4];
            h3[4 * q4 + 0] = fmaf(w.x, v, h3[4 * q4 + 0]);
            h3[4 * q4 + 1] = fmaf(w.y, v, h3[4 * q4 + 1]);
            h3[4 * q4 + 2] = fmaf(w.z, v, h3[4 * q4 + 2]);
            h3[4 * q4 + 3] = fmaf(w.w, v, h3[4 * q4 + 3]);
        }
    }
    #pragma unroll
    for (int q = 0; q < 16; q++) h3[q] = fmaxf(h3[q], 0.f);

    // layers 4+5: 16 -> 8 -> 1
    float z = sbc1[0];
    #pragma unroll
    for (int j = 0; j < 8; j++) {
        const float4* wbr = (const float4*)&sWb[j * 16];
        const float4 wA = wbr[0], wB = wbr[1], wC = wbr[2], wD = wbr[3];
        float s0 = sbb[j], s1 = 0.f, s2 = 0.f, s3 = 0.f;
        s0 = fmaf(wA.x, h3[0],  s0); s1 = fmaf(wA.y, h3[1],  s1);
        s2 = fmaf(wA.z, h3[2],  s2); s3 = fmaf(wA.w, h3[3],  s3);
        s0 = fmaf(wB.x, h3[4],  s0); s1 = fmaf(wB.y, h3[5],  s1);
        s2 = fmaf(wB.z, h3[6],  s2); s3 = fmaf(wB.w, h3[7],  s3);
        s0 = fmaf(wC.x, h3[8],  s0); s1 = fmaf(wC.y, h3[9],  s1);
        s2 = fmaf(wC.z, h3[10], s2); s3 = fmaf(wC.w, h3[11], s3);
        s0 = fmaf(wD.x, h3[12], s0); s1 = fmaf(wD.y, h3[13], s1);
        s2 = fmaf(wD.z, h3[14], s2); s3 = fmaf(wD.w, h3[15], s3);
        z = fmaf(sWc[j], fmaxf((s0 + s1) + (s2 + s3), 0.f), z);
    }

    const float sp = fmaxf(z, 0.f) + log1pf(expf(-fabsf(z)));
    scores[p] = sp;
    atomicAdd(&histL[__float_as_uint(sp) >> 16], 1u);   // LDS atomic
    __syncthreads();

    // merge private hist: <=256 nonzero bins per block
    for (int i = t; i < NB1; i += 256) {
        const unsigned v = histL[i];
        if (v) atomicAdd(&hist1[i], v);
    }
}

// ---------------------------------------------------------------------------
// K2: level-1 threshold + level-2 histogram. 64 blocks x 256 threads.
// Each block redundantly finds B* = max level-1 bin with suffix >= 64 and
// tail1 = suffix(B*+1) (< 64). Then scans its 1024-score slice: scores whose
// high-16 == B* contribute atomicAdd(hist2[low-16]) (participants spread
// over 65536 bins -> negligible contention). Block 0 publishes meta.
// ---------------------------------------------------------------------------
__global__ __launch_bounds__(256) void refine_kernel(
    const unsigned* __restrict__ hist1, const float* __restrict__ scores,
    unsigned* __restrict__ hist2, int* __restrict__ meta)
{
    __shared__ unsigned csum[256];
    __shared__ unsigned bsum[128];
    __shared__ int sh_c, sh_B;
    __shared__ unsigned sh_tail;
    const int t = threadIdx.x;

    {
        unsigned s = 0;
        const uint4* h4 = (const uint4*)(hist1 + t * 128);
        #pragma unroll
        for (int i = 0; i < 32; i++) {
            const uint4 v = h4[i];
            s += v.x + v.y + v.z + v.w;
        }
        csum[t] = s;
    }
    __syncthreads();
    for (int d = 1; d < 256; d <<= 1) {
        const unsigned v = (t + d < 256) ? csum[t + d] : 0u;
        __syncthreads();
        csum[t] += v;
        __syncthreads();
    }
    {
        const unsigned here = csum[t];
        const unsigned nxt = (t + 1 < 256) ? csum[t + 1] : 0u;
        if (here >= 64u && nxt < 64u) sh_c = t;
    }
    __syncthreads();
    const int cstar = sh_c;
    if (t < 128) bsum[t] = hist1[cstar * 128 + t];
    __syncthreads();
    {
        const unsigned ctail = (cstar + 1 < 256) ? csum[cstar + 1] : 0u;
        for (int d = 1; d < 128; d <<= 1) {
            unsigned v = 0u;
            if (t < 128 && t + d < 128) v = bsum[t + d];
            __syncthreads();
            if (t < 128) bsum[t] += v;
            __syncthreads();
        }
        if (t < 128) {
            const unsigned here = bsum[t] + ctail;
            const unsigned nxt = (t + 1 < 128) ? bsum[t + 1] + ctail : ctail;
            if (here >= 64u && nxt < 64u) { sh_B = cstar * 128 + t; sh_tail = nxt; }
        }
    }
    __syncthreads();
    const unsigned Bstar = (unsigned)sh_B;
    if (blockIdx.x == 0 && t == 0) { meta[0] = sh_B; meta[1] = (int)sh_tail; }

    // level-2 histogram over this block's slice
    const float4* s4 = (const float4*)scores;
    const int i = blockIdx.x * 256 + t;
    const float4 v = s4[i];
    unsigned b;
    b = __float_as_uint(v.x); if ((b >> 16) == Bstar) atomicAdd(&hist2[b & 0xFFFFu], 1u);
    b = __float_as_uint(v.y); if ((b >> 16) == Bstar) atomicAdd(&hist2[b & 0xFFFFu], 1u);
    b = __float_as_uint(v.z); if ((b >> 16) == Bstar) atomicAdd(&hist2[b & 0xFFFFu], 1u);
    b = __float_as_uint(v.w); if ((b >> 16) == Bstar) atomicAdd(&hist2[b & 0xFFFFu], 1u);
}

// ---------------------------------------------------------------------------
// K3: exact 32-bit threshold + compact. 64 blocks x 256 threads.
// T2 = max level-2 bin with tail1 + suffix2 >= 64; threshold32 = (B*<<16)|T2.
// Compact (hi > B*) || (hi == B* && lo >= T2): count = 64 + exact-value ties.
// ---------------------------------------------------------------------------
__global__ __launch_bounds__(256) void compact_kernel(
    const unsigned* __restrict__ hist2, const float* __restrict__ scores,
    int* __restrict__ meta, u64* __restrict__ cand)
{
    __shared__ unsigned csum[256];
    __shared__ unsigned bsum[256];
    __shared__ int sh_c, sh_T2;
    const int t = threadIdx.x;
    const unsigned Bstar = (unsigned)meta[0];
    const unsigned tail1 = (unsigned)meta[1];

    // chunk sums: thread t sums level-2 bins [t*256, t*256+256)
    {
        unsigned s = 0;
        const uint4* h4 = (const uint4*)(hist2 + t * 256);
        #pragma unroll
        for (int i = 0; i < 64; i++) {
            const uint4 v = h4[i];
            s += v.x + v.y + v.z + v.w;
        }
        csum[t] = s;
    }
    __syncthreads();
    for (int d = 1; d < 256; d <<= 1) {
        const unsigned v = (t + d < 256) ? csum[t + d] : 0u;
        __syncthreads();
        csum[t] += v;
        __syncthreads();
    }
    {
        const unsigned here = tail1 + csum[t];
        const unsigned nxt = tail1 + ((t + 1 < 256) ? csum[t + 1] : 0u);
        if (here >= 64u && nxt < 64u) sh_c = t;
    }
    __syncthreads();
    const int cstar = sh_c;
    bsum[t] = hist2[cstar * 256 + t];
    __syncthreads();
    {
        const unsigned ctail = tail1 + ((cstar + 1 < 256) ? csum[cstar + 1] : 0u);
        for (int d = 1; d < 256; d <<= 1) {
            const unsigned v = (t + d < 256) ? bsum[t + d] : 0u;
            __syncthreads();
            bsum[t] += v;
            __syncthreads();
        }
        const unsigned here = bsum[t] + ctail;
        const unsigned nxt = ((t + 1 < 256) ? bsum[t + 1] : 0u) + ctail;
        if (here >= 64u && nxt < 64u) sh_T2 = cstar * 256 + t;
    }
    __syncthreads();
    const unsigned T2 = (unsigned)sh_T2;

    // compact this block's 1024-point slice
    const float4* s4 = (const float4*)scores;
    const int i = blockIdx.x * 256 + t;
    const float4 v = s4[i];
    const int n0 = 4 * i;
    unsigned b; unsigned hi;
    b = __float_as_uint(v.x); hi = b >> 16;
    if (hi > Bstar || (hi == Bstar && (b & 0xFFFFu) >= T2)) { int p = atomicAdd(&meta[2], 1); if (p < CAND_CAP) cand[p] = ((u64)b << 32) | (unsigned)~(n0 + 0); }
    b = __float_as_uint(v.y); hi = b >> 16;
    if (hi > Bstar || (hi == Bstar && (b & 0xFFFFu) >= T2)) { int p = atomicAdd(&meta[2], 1); if (p < CAND_CAP) cand[p] = ((u64)b << 32) | (unsigned)~(n0 + 1); }
    b = __float_as_uint(v.z); hi = b >> 16;
    if (hi > Bstar || (hi == Bstar && (b & 0xFFFFu) >= T2)) { int p = atomicAdd(&meta[2], 1); if (p < CAND_CAP) cand[p] = ((u64)b << 32) | (unsigned)~(n0 + 2); }
    b = __float_as_uint(v.w); hi = b >> 16;
    if (hi > Bstar || (hi == Bstar && (b & 0xFFFFu) >= T2)) { int p = atomicAdd(&meta[2], 1); if (p < CAND_CAP) cand[p] = ((u64)b << 32) | (unsigned)~(n0 + 3); }
}

// ---------------------------------------------------------------------------
// K4: rank-select (count ~ 64-100) + gather. 1 block x 256.
// Key = (score_bits<<32) | ~idx -> exact lax.top_k order (value desc,
// lower idx first on ties). Keys unique -> ranks form a permutation.
// ---------------------------------------------------------------------------
__global__ __launch_bounds__(256) void final_kernel(
    const int* __restrict__ meta, const u64* __restrict__ cand,
    const float* __restrict__ src, float* __restrict__ out)
{
    __shared__ u64 keys[CAND_CAP];
    __shared__ int idxs[64];
    const int t = threadIdx.x;

    int count = meta[2];
    if (count > CAND_CAP) count = CAND_CAP;

    for (int i = t; i < count; i += 256) keys[i] = cand[i];
    __syncthreads();

    for (int i = t; i < count; i += 256) {
        const u64 me = keys[i];
        int r = 0;
        for (int j = 0; j < count; j++) r += (keys[j] > me);
        if (r < 64) idxs[r] = (int)~(unsigned)(me & 0xFFFFFFFFu);
    }
    __syncthreads();

    // out[b, k, c] = src[b, c, idx[k]]  -> flat e = b*384 + k*6 + c
    for (int e = t; e < 3072; e += 256) {
        const int b  = e / 384;
        const int rr = e % 384;
        const int kk = rr / 6;
        const int c  = rr % 6;
        out[e] = src[(b * 6 + c) * N_PTS + idxs[kk]];
    }
}

extern "C" void kernel_launch(void* const* d_in, const int* in_sizes, int n_in,
                              void* d_out, int out_size, void* d_ws, size_t ws_size,
                              hipStream_t stream)
{
    const float* src = (const float*)d_in[0];
    const float* W1 = (const float*)d_in[2];
    const float* b1 = (const float*)d_in[3];
    const float* W2 = (const float*)d_in[4];
    const float* b2 = (const float*)d_in[5];
    const float* Wa = (const float*)d_in[6];
    const float* ba = (const float*)d_in[7];
    const float* Wb = (const float*)d_in[8];
    const float* bb = (const float*)d_in[9];
    const float* Wc = (const float*)d_in[10];
    const float* bc = (const float*)d_in[11];

    char* ws = (char*)d_ws;
    float*    scores = (float*)ws;                          // 256 KB
    unsigned* hist1  = (unsigned*)(ws + 256 * 1024);        // 128 KB
    unsigned* hist2  = (unsigned*)(ws + 384 * 1024);        // 256 KB
    int*      meta   = (int*)(ws + 640 * 1024);             // 64 B
    u64*      cand   = (u64*)(ws + 640 * 1024 + 64);        // 32 KB
    float*    out    = (float*)d_out;

    // zero hist1+hist2+meta (contiguous): 98320 dwords; NO hipMemsetAsync
    // (R6 isolated in-graph memset at ~75us).
    const int nz = NB1 + NB2 + 16;
    zero_kernel<<<(nz + 255) / 256, 256, 0, stream>>>(hist1, nz);
    score_kernel<<<256, 256, 0, stream>>>(src, W1, b1, W2, b2, Wa, ba,
                                          Wb, bb, Wc, bc, scores, hist1);
    refine_kernel<<<64, 256, 0, stream>>>(hist1, scores, hist2, meta);
    compact_kernel<<<64, 256, 0, stream>>>(hist2, scores, meta, cand);
    final_kernel<<<1, 256, 0, stream>>>(meta, cand, src, out);
}